// Round 18
// baseline (253.653 us; speedup 1.0000x reference)
//
#include <hip/hip_runtime.h>

typedef __bf16 bf16;
typedef __bf16 bf16x8 __attribute__((ext_vector_type(8)));
typedef float f32x4 __attribute__((ext_vector_type(4)));
typedef float f32x16 __attribute__((ext_vector_type(16)));

#define GLDS16(gp, lp) __builtin_amdgcn_global_load_lds( \
    (__attribute__((address_space(1))) void*)(gp), \
    (__attribute__((address_space(3))) void*)(lp), 16, 0, 0)

__device__ inline float ex2(float x) { return exp2f(x); }

// gelu(tanh approx) == x * sigmoid(2*0.7978845608*(x+0.044715x^3)) — exact identity.
__device__ inline float gelu_fast(float x) {
    float t = ex2(-2.3022081702f * (x + 0.044715f * x * x * x));
    return x * __builtin_amdgcn_rcpf(1.0f + t);
}

// cross-half pair swap: a' = {a.lo | b.lo-from-partner}, b' = {a.hi-from-partner | b.hi}
__device__ inline void plswap(int h, unsigned& a, unsigned& b) {
#if __has_builtin(__builtin_amdgcn_permlane32_swap)
    typedef unsigned u32x2_ __attribute__((ext_vector_type(2)));
    u32x2_ r = __builtin_amdgcn_permlane32_swap(a, b, false, false);
    a = r[0]; b = r[1];
#else
    unsigned sa = (unsigned)__shfl_xor((int)a, 32, 64);
    unsigned sb = (unsigned)__shfl_xor((int)b, 32, 64);
    unsigned na = h ? sb : a;
    unsigned nb = h ? b : sa;
    a = na; b = nb;
#endif
}

// ---------------- merged pre-processing: f2b(x) + transpose(W1) + transpose(W2) ----
__global__ __launch_bounds__(256) void prep_kernel(const float* __restrict__ x,
                                                   bf16* __restrict__ xb,
                                                   const float* __restrict__ W1,
                                                   bf16* __restrict__ w1t,
                                                   const float* __restrict__ W2,
                                                   bf16* __restrict__ w2t) {
    int bid = blockIdx.x;
    if (bid < 4096) {
        long i = ((long)bid * 256 + threadIdx.x) * 4;
        float4 v = *(const float4*)&x[i];
        xb[i + 0] = (bf16)v.x;
        xb[i + 1] = (bf16)v.y;
        xb[i + 2] = (bf16)v.z;
        xb[i + 3] = (bf16)v.w;
        return;
    }
    const float* W;
    bf16* WT;
    int K, N, n0, k0;
    if (bid < 11264) {
        int t = bid - 4096;          // W1: 1024 x 7168
        W = W1; WT = w1t; K = 1024; N = 7168;
        n0 = (t % 224) * 32; k0 = (t / 224) * 32;
    } else {
        int t = bid - 11264;         // W2: 5120 x 1024
        W = W2; WT = w2t; K = 5120; N = 1024;
        n0 = (t % 32) * 32; k0 = (t / 32) * 32;
    }
    __shared__ float tile[32][33];
    int tx = threadIdx.x & 31;
    int ty = threadIdx.x >> 5;
#pragma unroll
    for (int i = 0; i < 4; ++i)
        tile[ty + i * 8][tx] = W[(long)(k0 + ty + i * 8) * N + n0 + tx];
    __syncthreads();
#pragma unroll
    for (int i = 0; i < 4; ++i)
        WT[(long)(n0 + ty + i * 8) * K + k0 + tx] = (bf16)tile[tx][ty + i * 8];
}

// ---------------- GEMM1: 128x128 BK=64 + FUSED qkv epilogue + XCD swizzle ----
__global__ __launch_bounds__(256) void gemm1_fused(const bf16* __restrict__ A,
                                                   const bf16* __restrict__ BT,
                                                   const float* __restrict__ bias,
                                                   const float* __restrict__ pe,
                                                   const float* __restrict__ qsc,
                                                   const float* __restrict__ ksc,
                                                   bf16* __restrict__ qb_,
                                                   bf16* __restrict__ kb_,
                                                   bf16* __restrict__ vsrc,
                                                   bf16* __restrict__ cat,
                                                   int K) {
    __shared__ __align__(16) char Asm[128 * 128];
    __shared__ __align__(16) char Bsm[128 * 128];
    int tid = threadIdx.x;
    int w = tid >> 6, l = tid & 63;
    int wr = w >> 1, wc = w & 1;
    // XCD swizzle: 1792 blocks = 8 XCDs x 224 (7 N-panels x 32 M-tiles each)
    int bid = blockIdx.x;
    int swz = (bid & 7) * 224 + (bid >> 3);
    int bm = (swz & 31) * 128;
    int bn = (swz >> 5) * 128;

    f32x4 acc[4][4] = {};

    int fr = l & 15;
    int g16 = (l >> 4) * 16;
    int xsw = (fr & 7) << 4;

    int srow = tid >> 3;
    int sg8 = ((tid & 7) ^ (srow & 7)) * 8;
    int dstoff = tid * 16;

    int nk = K >> 6;
    for (int kt = 0; kt < nk; ++kt) {
        int k0 = kt * 64;
#pragma unroll
        for (int gg = 0; gg < 4; ++gg) {
            const bf16* ga = A + (long)(bm + gg * 32 + srow) * K + k0 + sg8;
            GLDS16(ga, Asm + gg * 4096 + dstoff);
            const bf16* gb = BT + (long)(bn + gg * 32 + srow) * K + k0 + sg8;
            GLDS16(gb, Bsm + gg * 4096 + dstoff);
        }
        asm volatile("s_waitcnt vmcnt(0)" ::: "memory");
        __syncthreads();

#pragma unroll
        for (int kk = 0; kk < 2; ++kk) {
            int koff = (kk * 64 + g16) ^ xsw;
            bf16x8 af[4], bfr[4];
#pragma unroll
            for (int m = 0; m < 4; ++m)
                af[m] = *(const bf16x8*)(Asm + (wr * 64 + m * 16 + fr) * 128 + koff);
#pragma unroll
            for (int n = 0; n < 4; ++n)
                bfr[n] = *(const bf16x8*)(Bsm + (wc * 64 + n * 16 + fr) * 128 + koff);
#pragma unroll
            for (int m = 0; m < 4; ++m)
#pragma unroll
                for (int n = 0; n < 4; ++n)
                    acc[m][n] = __builtin_amdgcn_mfma_f32_16x16x32_bf16(af[m], bfr[n], acc[m][n], 0, 0, 0);
        }
        __syncthreads();
    }

    int orow0 = bm + wr * 64;
    int ocol0 = bn + wc * 64;

    if (bn < 2048) {
        bool isq = (bn < 1024);
        const float* sc = isq ? qsc : ksc;
        bf16* dst = isq ? qb_ : kb_;
#pragma unroll
        for (int m = 0; m < 4; ++m) {
#pragma unroll
            for (int r = 0; r < 4; ++r) {
                int row = orow0 + m * 16 + (l >> 4) * 4 + r;
                int lpos = row & 2047;
                int bb = row >> 11;
                float v[4];
                float ss = 0.0f;
#pragma unroll
                for (int n = 0; n < 4; ++n) {
                    int col = ocol0 + n * 16 + fr;
                    v[n] = acc[m][n][r] + bias[col];
                    ss += v[n] * v[n];
                }
#pragma unroll
                for (int off = 1; off < 16; off <<= 1)
                    ss += __shfl_xor(ss, off, 16);
                float rr = rsqrtf(ss * (1.0f / 64.0f) + 1e-6f);
#pragma unroll
                for (int n = 0; n < 4; ++n) {
                    int col = ocol0 + n * 16 + fr;
                    int d = col & 63;
                    int hh = (col & 1023) >> 6;
                    float qn = v[n] * rr * sc[d];
                    float pv = __shfl_xor(qn, 1, 16);
                    float qe = (d & 1) ? pv : qn;
                    float qo = (d & 1) ? qn : pv;
                    float pe0 = pe[lpos * 128 + (d >> 1) * 4 + (d & 1) * 2 + 0];
                    float pe1 = pe[lpos * 128 + (d >> 1) * 4 + (d & 1) * 2 + 1];
                    float ov = pe0 * qe + pe1 * qo;
                    if (isq) ov *= 0.18033688011112042f;   // 0.125*log2e
                    dst[((long)(bb * 16 + hh) * 2048 + lpos) * 64 + d] = (bf16)ov;
                }
            }
        }
    } else if (bn < 3072) {
#pragma unroll
        for (int m = 0; m < 4; ++m) {
            int row = orow0 + m * 16 + (l >> 4) * 4;
#pragma unroll
            for (int n = 0; n < 4; ++n) {
                int col = ocol0 + n * 16 + fr;
                float bv = bias[col];
#pragma unroll
                for (int r = 0; r < 4; ++r)
                    vsrc[(long)(row + r) * 1024 + col - 2048] = (bf16)(acc[m][n][r] + bv);
            }
        }
    } else {
#pragma unroll
        for (int m = 0; m < 4; ++m) {
            int row = orow0 + m * 16 + (l >> 4) * 4;
#pragma unroll
            for (int n = 0; n < 4; ++n) {
                int col = ocol0 + n * 16 + fr;
                float bv = bias[col];
#pragma unroll
                for (int r = 0; r < 4; ++r) {
                    float v = acc[m][n][r] + bv;
                    cat[(long)(row + r) * 5120 + 1024 + col - 3072] = (bf16)gelu_fast(v);
                }
            }
        }
    }
}

// ---------------- GEMM2: 256x256 8-phase split-K, bf16 partials ----------
#define STA(tile, ch) if ((tile) < NT) { \
    const bf16* s_ = gA + (tile) * 64 + (ch) * 32; \
    char* d_ = lds + ((tile) & 1) * 65536 + (ch) * 16384 + tid * 16; \
    GLDS16(s_, d_); GLDS16(s_ + (long)128 * K, d_ + 8192); }

#define STB(tile, ch) if ((tile) < NT) { \
    const bf16* s_ = gB + (tile) * 64 + (ch) * 32; \
    char* d_ = lds + ((tile) & 1) * 65536 + 32768 + (ch) * 16384 + tid * 16; \
    GLDS16(s_, d_); GLDS16(s_ + (long)128 * K, d_ + 8192); }

#define PH(tb, mh, kh, RB, STAGE_STMT, WAITN) do { \
    { const char* Ab_ = lds + (tb) * 65536 + (kh) * 16384; \
      const char* Bb_ = lds + (tb) * 65536 + 32768 + (kh) * 16384; \
      if (RB) { \
        _Pragma("unroll") for (int n_ = 0; n_ < 4; ++n_) \
          bfrag[n_] = *(const bf16x8*)(Bb_ + (wc * 64 + n_ * 16 + fr) * 64 + aslot); } \
      _Pragma("unroll") for (int i_ = 0; i_ < 4; ++i_) \
          afrag[i_] = *(const bf16x8*)(Ab_ + (wr * 128 + (mh) * 64 + i_ * 16 + fr) * 64 + aslot); \
    } \
    STAGE_STMT; \
    asm volatile("s_waitcnt vmcnt(" #WAITN ")" ::: "memory"); \
    asm volatile("s_barrier" ::: "memory"); \
    __builtin_amdgcn_s_setprio(1); \
    _Pragma("unroll") for (int n_ = 0; n_ < 4; ++n_) \
      _Pragma("unroll") for (int i_ = 0; i_ < 4; ++i_) \
        acc[(mh) * 4 + i_][n_] = __builtin_amdgcn_mfma_f32_16x16x32_bf16(afrag[i_], bfrag[n_], acc[(mh) * 4 + i_][n_], 0, 0, 0); \
    __builtin_amdgcn_s_setprio(0); \
    asm volatile("s_barrier" ::: "memory"); \
} while (0)

__global__ __launch_bounds__(512, 2) void gemm8p_sk(const bf16* __restrict__ A_,
                                                    const bf16* __restrict__ BT_,
                                                    bf16* __restrict__ part,
                                                    int M, int N, int K, int kch) {
    __shared__ __align__(16) char lds[131072];

    int bx = blockIdx.x, by = blockIdx.y;
    int k0base = blockIdx.z * kch;
    int bm = bx * 256, bn = by * 256;
    int NT = kch >> 6;

    int tid = threadIdx.x;
    int w = tid >> 6, l = tid & 63;
    int wr = w >> 2, wc = w & 3;
    int fr = l & 15;
    int aslot = (((l >> 4) ^ ((fr >> 1) & 3)) << 4);

    int srow0 = tid >> 2;
    int sgoff = (((tid & 3) ^ ((srow0 >> 1) & 3)) << 3);
    const bf16* gA = A_ + (long)(bm + srow0) * K + k0base + sgoff;
    const bf16* gB = BT_ + (long)(bn + srow0) * K + k0base + sgoff;

    f32x4 acc[8][4] = {};
    bf16x8 bfrag[4];
    bf16x8 afrag[4];

    STA(0, 0); STA(0, 1); STB(0, 0); STB(0, 1);
    STB(1, 0); STA(1, 0); STB(1, 1);
    asm volatile("s_waitcnt vmcnt(0)" ::: "memory");
    asm volatile("s_barrier" ::: "memory");

    int NI = NT >> 1;
    for (int i = 0; i < NI; ++i) {
        int t1 = 2 * i + 1, t2 = 2 * i + 2, t3 = 2 * i + 3;
        if (i == NI - 1) {
            PH(0, 0, 0, true, STA(t1, 1), 0);
        } else {
            PH(0, 0, 0, true, STA(t1, 1), 10);
        }
        PH(0, 1, 0, false, STB(t2, 0), 10);
        PH(0, 0, 1, true,  STA(t2, 0), 10);
        PH(0, 1, 1, false, STB(t2, 1), 10);
        PH(1, 0, 0, true,  STA(t2, 1), 10);
        PH(1, 1, 0, false, STB(t3, 0), 10);
        PH(1, 0, 1, true,  STA(t3, 0), 10);
        PH(1, 1, 1, false, STB(t3, 1), 10);
    }

    bf16* cz = part + (long)blockIdx.z * M * N;
    int r4 = (l >> 4) * 4;
#pragma unroll
    for (int mi = 0; mi < 8; ++mi) {
        int row = bm + wr * 128 + mi * 16 + r4;
#pragma unroll
        for (int n = 0; n < 4; ++n) {
            int col = bn + wc * 64 + n * 16 + fr;
#pragma unroll
            for (int r = 0; r < 4; ++r)
                cz[(long)(row + r) * N + col] = (bf16)acc[mi][n][r];
        }
    }
}

// out[i] = b2[i & 1023] + sum_z part[z][i]   (bf16 partials, N = 1024)
__global__ __launch_bounds__(256) void reduce4_kernel(const bf16* __restrict__ part,
                                                      const float* __restrict__ b2,
                                                      float* __restrict__ out) {
    const long stride = 4096L * 1024;
    long e0 = ((long)blockIdx.x * 256 + threadIdx.x) * 8;
    float s[8];
    int boff = (int)(e0 & 1023);
#pragma unroll
    for (int j = 0; j < 8; ++j) s[j] = b2[boff + j];
#pragma unroll
    for (int z = 0; z < 4; ++z) {
        bf16x8 v = *(const bf16x8*)&part[z * stride + e0];
#pragma unroll
        for (int j = 0; j < 8; ++j) s[j] += (float)v[j];
    }
    *(float4*)&out[e0] = *(float4*)&s[0];
    *(float4*)&out[e0 + 4] = *(float4*)&s[4];
}

// ---------------- V transpose: vsrc[4096][1024] -> vT[bh][d][lpos] ----------------
__global__ __launch_bounds__(256) void vtrans_kernel(const bf16* __restrict__ vsrc,
                                                     bf16* __restrict__ vT) {
    __shared__ unsigned short tile[64 * 65];
    int bh = blockIdx.x;
    int b = bh >> 4, hh = bh & 15;
    int l0 = blockIdx.y * 64;
    int tid = threadIdx.x;

    int r = tid >> 3, c = tid & 7;
#pragma unroll
    for (int p = 0; p < 2; ++p) {
        int row = r + p * 32;
        const bf16* src = vsrc + (long)(b * 2048 + l0 + row) * 1024 + hh * 64 + c * 8;
        bf16x8 v = *(const bf16x8*)src;
        union { bf16x8 v; unsigned short s[8]; } u; u.v = v;
#pragma unroll
        for (int e = 0; e < 8; ++e) tile[row * 65 + c * 8 + e] = u.s[e];
    }
    __syncthreads();
#pragma unroll
    for (int p = 0; p < 2; ++p) {
        int idx = tid + p * 256;
        int d = idx >> 3, kg = idx & 7;
        union { bf16x8 v; unsigned short s[8]; } u;
#pragma unroll
        for (int e = 0; e < 8; ++e) u.s[e] = tile[(kg * 8 + e) * 65 + d];
        *(bf16x8*)&vT[((long)bh * 64 + d) * 2048 + l0 + kg * 8] = u.v;
    }
}

// ---------------- Flash attention: in-register P via permlane32_swap ----------
// A-operand layout (HW-verified via the previously-working LDS route):
// pa[s], lane (h,ln), elem e  <->  P[ln][16s + 8h + e].
// Owned p's: kv(r) = (r&3) + 8*(r>>2) + 4h (+32 for S1). With packed words
// w0[t]=pack(p[4t],p[4t+1]), w1[t]=pack(p[4t+2],p[4t+3]) the fragment is
// u0,u2 = permlane32_swap(w0[2s'], w0[2s'+1]); u1,u3 = swap(w1[2s'], w1[2s'+1]).
__global__ __launch_bounds__(256) void attn_kernel(const bf16* __restrict__ qg,
                                                   const bf16* __restrict__ kg_,
                                                   const bf16* __restrict__ vT,
                                                   bf16* __restrict__ cat) {
    __shared__ __align__(16) char lds[49152];
    // K bufs: 0..24KB; V bufs: 24..48KB (3 rotating 8KB bufs each)

    int bidx = blockIdx.x;
    int bh = bidx & 31;
    int qblk = bidx >> 5;
    int b = bh >> 4, hh = bh & 15;
    int tid = threadIdx.x;
    int wv = tid >> 6, l = tid & 63;
    int h = l >> 5, ln = l & 31;
    int sw = (ln & 7) << 4;

    const bf16* qbase = qg + ((long)bh * 2048 + qblk * 128 + wv * 32 + ln) * 64 + h * 8;
    bf16x8 qf[4];
#pragma unroll
    for (int ds = 0; ds < 4; ++ds) qf[ds] = *(const bf16x8*)(qbase + ds * 16);

    f32x16 Oa0 = {}, Oa1 = {};
    float lsum = 0.0f;

    int kr = tid >> 3, kg = tid & 7;
    int swb = (kg * 16) ^ ((kr & 7) << 4);
    const bf16* gK = kg_ + ((long)bh * 2048 + kr) * 64 + kg * 8;
    const bf16* gV = vT + ((long)bh * 64 + kr) * 2048 + kg * 8;

    bf16x8 rk0 = *(const bf16x8*)gK;
    bf16x8 rk1 = *(const bf16x8*)(gK + 32 * 64);
    bf16x8 rv0 = *(const bf16x8*)gV;
    bf16x8 rv1 = *(const bf16x8*)(gV + 32 * 2048);
    *(bf16x8*)(lds + kr * 128 + swb) = rk0;
    *(bf16x8*)(lds + (kr + 32) * 128 + swb) = rk1;
    *(bf16x8*)(lds + 24576 + kr * 128 + swb) = rv0;
    *(bf16x8*)(lds + 24576 + (kr + 32) * 128 + swb) = rv1;
    __syncthreads();

    int bufR = 0;
    for (int t = 0; t < 32; ++t) {
        if (t < 31) {
            rk0 = *(const bf16x8*)(gK + (long)(t + 1) * 4096);
            rk1 = *(const bf16x8*)(gK + (long)(t + 1) * 4096 + 32 * 64);
            rv0 = *(const bf16x8*)(gV + (t + 1) * 64);
            rv1 = *(const bf16x8*)(gV + (t + 1) * 64 + 32 * 2048);
        }
        const char* Kc = lds + bufR * 8192;
        const char* Vc = lds + 24576 + bufR * 8192;

        f32x16 S0 = {}, S1 = {};
        __builtin_amdgcn_s_setprio(1);
#pragma unroll
        for (int ds = 0; ds < 4; ++ds) {
            bf16x8 kf0 = *(const bf16x8*)(Kc + ln * 128 + ((ds * 32 + h * 16) ^ sw));
            bf16x8 kf1 = *(const bf16x8*)(Kc + (32 + ln) * 128 + ((ds * 32 + h * 16) ^ sw));
            S0 = __builtin_amdgcn_mfma_f32_32x32x16_bf16(kf0, qf[ds], S0, 0, 0, 0);
            S1 = __builtin_amdgcn_mfma_f32_32x32x16_bf16(kf1, qf[ds], S1, 0, 0, 0);
        }
        __builtin_amdgcn_s_setprio(0);

        // ---- P = exp2(S - 12); assemble A-fragments fully in registers ----
        bf16x8 pa[4];
#pragma unroll
        for (int H = 0; H < 2; ++H) {
            float p[16];
#pragma unroll
            for (int r = 0; r < 16; ++r) {
                float v = ex2((H ? S1[r] : S0[r]) - 12.0f);
                p[r] = v;
                lsum += v;
            }
            unsigned w0[4], w1[4];
#pragma unroll
            for (int tt = 0; tt < 4; ++tt) {
                union { bf16 bb[2]; unsigned u; } pk0, pk1;
                pk0.bb[0] = (bf16)p[4 * tt + 0];
                pk0.bb[1] = (bf16)p[4 * tt + 1];
                pk1.bb[0] = (bf16)p[4 * tt + 2];
                pk1.bb[1] = (bf16)p[4 * tt + 3];
                w0[tt] = pk0.u;
                w1[tt] = pk1.u;
            }
#pragma unroll
            for (int sp = 0; sp < 2; ++sp) {
                unsigned A0 = w0[2 * sp], B0 = w0[2 * sp + 1];
                unsigned A1 = w1[2 * sp], B1 = w1[2 * sp + 1];
                plswap(h, A0, B0);
                plswap(h, A1, B1);
                union { unsigned u[4]; bf16x8 v; } pk;
                pk.u[0] = A0; pk.u[1] = A1; pk.u[2] = B0; pk.u[3] = B1;
                pa[H * 2 + sp] = pk.v;
            }
        }

        __builtin_amdgcn_s_setprio(1);
#pragma unroll
        for (int s = 0; s < 4; ++s) {
            bf16x8 vf0 = *(const bf16x8*)(Vc + ln * 128 + ((s * 32 + h * 16) ^ sw));
            bf16x8 vf1 = *(const bf16x8*)(Vc + (32 + ln) * 128 + ((s * 32 + h * 16) ^ sw));
            Oa0 = __builtin_amdgcn_mfma_f32_32x32x16_bf16(pa[s], vf0, Oa0, 0, 0, 0);
            Oa1 = __builtin_amdgcn_mfma_f32_32x32x16_bf16(pa[s], vf1, Oa1, 0, 0, 0);
        }
        __builtin_amdgcn_s_setprio(0);

        if (t < 31) {
            int bufW = (bufR == 2) ? 0 : bufR + 1;
            *(bf16x8*)(lds + bufW * 8192 + kr * 128 + swb) = rk0;
            *(bf16x8*)(lds + bufW * 8192 + (kr + 32) * 128 + swb) = rk1;
            *(bf16x8*)(lds + 24576 + bufW * 8192 + kr * 128 + swb) = rv0;
            *(bf16x8*)(lds + 24576 + bufW * 8192 + (kr + 32) * 128 + swb) = rv1;
        }
        __syncthreads();
        bufR = (bufR == 2) ? 0 : bufR + 1;
    }

    lsum += __shfl_xor(lsum, 32, 64);

#pragma unroll
    for (int r = 0; r < 16; ++r) {
        int rowq = (r & 3) + 8 * (r >> 2) + 4 * h;
        float ls = __shfl(lsum, rowq, 64);
        float inv = 1.0f / ls;
        long trow = (long)b * 2048 + qblk * 128 + wv * 32 + rowq;
        cat[trow * 5120 + hh * 64 + ln] = (bf16)(Oa0[r] * inv);
        cat[trow * 5120 + hh * 64 + 32 + ln] = (bf16)(Oa1[r] * inv);
    }
}

// ---------------- launch ----------------

extern "C" void kernel_launch(void* const* d_in, const int* in_sizes, int n_in,
                              void* d_out, int out_size, void* d_ws, size_t ws_size,
                              hipStream_t stream) {
    const float* x  = (const float*)d_in[0];
    const float* pe = (const float*)d_in[1];
    const float* W1 = (const float*)d_in[2];
    const float* b1 = (const float*)d_in[3];
    const float* W2 = (const float*)d_in[4];
    const float* b2 = (const float*)d_in[5];
    const float* qs = (const float*)d_in[6];
    const float* ks = (const float*)d_in[7];
    float* out = (float*)d_out;

    char* ws = (char*)d_ws;
    bf16* xb   = (bf16*)(ws);                 // 4096*1024*2      =  8388608
    bf16* w1t  = (bf16*)(ws + 8388608);       // 7168*1024*2     = 14680064
    bf16* w2t  = (bf16*)(ws + 23068672);      // 1024*5120*2     = 10485760
    bf16* vsrc = (bf16*)(ws + 33554432);      // 4096*1024*2     =  8388608
    bf16* qb   = (bf16*)(ws + 92274688);      // 32*2048*64*2    =  8388608
    bf16* kb   = (bf16*)(ws + 100663296);     //                 =  8388608
    bf16* vT   = (bf16*)(ws + 109051904);     //                 =  8388608
    bf16* cat  = (bf16*)(ws + 117440512);     // 4096*5120*2     = 41943040
    // bf16 split-K partials (4 x 4096 x 1024 x 2B) overlap vsrc/qb (dead by then).
    bf16* part = (bf16*)(ws + 33554432);

    prep_kernel<<<16384, 256, 0, stream>>>(x, xb, W1, w1t, W2, w2t);

    gemm1_fused<<<dim3(1792), 256, 0, stream>>>(xb, w1t, b1, pe, qs, ks,
                                                qb, kb, vsrc, cat, 1024);

    vtrans_kernel<<<dim3(32, 32), 256, 0, stream>>>(vsrc, vT);

    attn_kernel<<<512, 256, 0, stream>>>(qb, kb, vT, cat);

    gemm8p_sk<<<dim3(16, 4, 4), 512, 0, stream>>>(cat, w2t, part, 4096, 1024, 5120, 1280);
    reduce4_kernel<<<2048, 256, 0, stream>>>(part, b2, out);
}

// Round 19
// 242.145 us; speedup vs baseline: 1.0475x; 1.0475x over previous
//
#include <hip/hip_runtime.h>

typedef __bf16 bf16;
typedef __bf16 bf16x8 __attribute__((ext_vector_type(8)));
typedef float f32x4 __attribute__((ext_vector_type(4)));
typedef float f32x16 __attribute__((ext_vector_type(16)));

#define GLDS16(gp, lp) __builtin_amdgcn_global_load_lds( \
    (__attribute__((address_space(1))) void*)(gp), \
    (__attribute__((address_space(3))) void*)(lp), 16, 0, 0)

__device__ inline float ex2(float x) { return exp2f(x); }

// gelu(tanh approx) == x * sigmoid(2*0.7978845608*(x+0.044715x^3)) — exact identity.
__device__ inline float gelu_fast(float x) {
    float t = ex2(-2.3022081702f * (x + 0.044715f * x * x * x));
    return x * __builtin_amdgcn_rcpf(1.0f + t);
}

// cross-half pair swap: a' = {a.lo | b.lo-from-partner}, b' = {a.hi-from-partner | b.hi}
__device__ inline void plswap(int h, unsigned& a, unsigned& b) {
#if __has_builtin(__builtin_amdgcn_permlane32_swap)
    typedef unsigned u32x2_ __attribute__((ext_vector_type(2)));
    u32x2_ r = __builtin_amdgcn_permlane32_swap(a, b, false, false);
    a = r[0]; b = r[1];
#else
    unsigned sa = (unsigned)__shfl_xor((int)a, 32, 64);
    unsigned sb = (unsigned)__shfl_xor((int)b, 32, 64);
    unsigned na = h ? sb : a;
    unsigned nb = h ? b : sa;
    a = na; b = nb;
#endif
}

// ---------------- merged pre-processing: f2b(x) + transpose(W1) + transpose(W2) ----
__global__ __launch_bounds__(256) void prep_kernel(const float* __restrict__ x,
                                                   bf16* __restrict__ xb,
                                                   const float* __restrict__ W1,
                                                   bf16* __restrict__ w1t,
                                                   const float* __restrict__ W2,
                                                   bf16* __restrict__ w2t) {
    int bid = blockIdx.x;
    if (bid < 4096) {
        long i = ((long)bid * 256 + threadIdx.x) * 4;
        float4 v = *(const float4*)&x[i];
        xb[i + 0] = (bf16)v.x;
        xb[i + 1] = (bf16)v.y;
        xb[i + 2] = (bf16)v.z;
        xb[i + 3] = (bf16)v.w;
        return;
    }
    const float* W;
    bf16* WT;
    int K, N, n0, k0;
    if (bid < 11264) {
        int t = bid - 4096;          // W1: 1024 x 7168
        W = W1; WT = w1t; K = 1024; N = 7168;
        n0 = (t % 224) * 32; k0 = (t / 224) * 32;
    } else {
        int t = bid - 11264;         // W2: 5120 x 1024
        W = W2; WT = w2t; K = 5120; N = 1024;
        n0 = (t % 32) * 32; k0 = (t / 32) * 32;
    }
    __shared__ float tile[32][33];
    int tx = threadIdx.x & 31;
    int ty = threadIdx.x >> 5;
#pragma unroll
    for (int i = 0; i < 4; ++i)
        tile[ty + i * 8][tx] = W[(long)(k0 + ty + i * 8) * N + n0 + tx];
    __syncthreads();
#pragma unroll
    for (int i = 0; i < 4; ++i)
        WT[(long)(n0 + ty + i * 8) * K + k0 + tx] = (bf16)tile[tx][ty + i * 8];
}

// ---------------- GEMM1: 128x128 BK=64 + FUSED qkv epilogue (grid 32x56) ----
// NOTE: default linear dispatch gives each XCD a ~4Mtile x 7Npanel concurrent
// rectangle (A 1MB + B 1.8MB, L2-resident). Round-18's XCD swizzle broke this
// (FETCH 74 -> 143 MB) — do NOT re-add it.
__global__ __launch_bounds__(256) void gemm1_fused(const bf16* __restrict__ A,
                                                   const bf16* __restrict__ BT,
                                                   const float* __restrict__ bias,
                                                   const float* __restrict__ pe,
                                                   const float* __restrict__ qsc,
                                                   const float* __restrict__ ksc,
                                                   bf16* __restrict__ qb_,
                                                   bf16* __restrict__ kb_,
                                                   bf16* __restrict__ vsrc,
                                                   bf16* __restrict__ cat,
                                                   int K) {
    __shared__ __align__(16) char Asm[128 * 128];
    __shared__ __align__(16) char Bsm[128 * 128];
    int tid = threadIdx.x;
    int w = tid >> 6, l = tid & 63;
    int wr = w >> 1, wc = w & 1;
    int bm = blockIdx.x * 128;
    int bn = blockIdx.y * 128;

    f32x4 acc[4][4] = {};

    int fr = l & 15;
    int g16 = (l >> 4) * 16;
    int xsw = (fr & 7) << 4;

    int srow = tid >> 3;
    int sg8 = ((tid & 7) ^ (srow & 7)) * 8;
    int dstoff = tid * 16;

    int nk = K >> 6;
    for (int kt = 0; kt < nk; ++kt) {
        int k0 = kt * 64;
#pragma unroll
        for (int gg = 0; gg < 4; ++gg) {
            const bf16* ga = A + (long)(bm + gg * 32 + srow) * K + k0 + sg8;
            GLDS16(ga, Asm + gg * 4096 + dstoff);
            const bf16* gb = BT + (long)(bn + gg * 32 + srow) * K + k0 + sg8;
            GLDS16(gb, Bsm + gg * 4096 + dstoff);
        }
        asm volatile("s_waitcnt vmcnt(0)" ::: "memory");
        __syncthreads();

#pragma unroll
        for (int kk = 0; kk < 2; ++kk) {
            int koff = (kk * 64 + g16) ^ xsw;
            bf16x8 af[4], bfr[4];
#pragma unroll
            for (int m = 0; m < 4; ++m)
                af[m] = *(const bf16x8*)(Asm + (wr * 64 + m * 16 + fr) * 128 + koff);
#pragma unroll
            for (int n = 0; n < 4; ++n)
                bfr[n] = *(const bf16x8*)(Bsm + (wc * 64 + n * 16 + fr) * 128 + koff);
#pragma unroll
            for (int m = 0; m < 4; ++m)
#pragma unroll
                for (int n = 0; n < 4; ++n)
                    acc[m][n] = __builtin_amdgcn_mfma_f32_16x16x32_bf16(af[m], bfr[n], acc[m][n], 0, 0, 0);
        }
        __syncthreads();
    }

    int orow0 = bm + wr * 64;
    int ocol0 = bn + wc * 64;

    if (bn < 2048) {
        bool isq = (bn < 1024);
        const float* sc = isq ? qsc : ksc;
        bf16* dst = isq ? qb_ : kb_;
#pragma unroll
        for (int m = 0; m < 4; ++m) {
#pragma unroll
            for (int r = 0; r < 4; ++r) {
                int row = orow0 + m * 16 + (l >> 4) * 4 + r;
                int lpos = row & 2047;
                int bb = row >> 11;
                float v[4];
                float ss = 0.0f;
#pragma unroll
                for (int n = 0; n < 4; ++n) {
                    int col = ocol0 + n * 16 + fr;
                    v[n] = acc[m][n][r] + bias[col];
                    ss += v[n] * v[n];
                }
#pragma unroll
                for (int off = 1; off < 16; off <<= 1)
                    ss += __shfl_xor(ss, off, 16);
                float rr = rsqrtf(ss * (1.0f / 64.0f) + 1e-6f);
#pragma unroll
                for (int n = 0; n < 4; ++n) {
                    int col = ocol0 + n * 16 + fr;
                    int d = col & 63;
                    int hh = (col & 1023) >> 6;
                    float qn = v[n] * rr * sc[d];
                    float pv = __shfl_xor(qn, 1, 16);
                    float qe = (d & 1) ? pv : qn;
                    float qo = (d & 1) ? qn : pv;
                    float pe0 = pe[lpos * 128 + (d >> 1) * 4 + (d & 1) * 2 + 0];
                    float pe1 = pe[lpos * 128 + (d >> 1) * 4 + (d & 1) * 2 + 1];
                    float ov = pe0 * qe + pe1 * qo;
                    if (isq) ov *= 0.18033688011112042f;   // 0.125*log2e
                    dst[((long)(bb * 16 + hh) * 2048 + lpos) * 64 + d] = (bf16)ov;
                }
            }
        }
    } else if (bn < 3072) {
#pragma unroll
        for (int m = 0; m < 4; ++m) {
            int row = orow0 + m * 16 + (l >> 4) * 4;
#pragma unroll
            for (int n = 0; n < 4; ++n) {
                int col = ocol0 + n * 16 + fr;
                float bv = bias[col];
#pragma unroll
                for (int r = 0; r < 4; ++r)
                    vsrc[(long)(row + r) * 1024 + col - 2048] = (bf16)(acc[m][n][r] + bv);
            }
        }
    } else {
#pragma unroll
        for (int m = 0; m < 4; ++m) {
            int row = orow0 + m * 16 + (l >> 4) * 4;
#pragma unroll
            for (int n = 0; n < 4; ++n) {
                int col = ocol0 + n * 16 + fr;
                float bv = bias[col];
#pragma unroll
                for (int r = 0; r < 4; ++r) {
                    float v = acc[m][n][r] + bv;
                    cat[(long)(row + r) * 5120 + 1024 + col - 3072] = (bf16)gelu_fast(v);
                }
            }
        }
    }
}

// ---------------- GEMM2: 256x256 8-phase split-K, bf16 partials ----------
#define STA(tile, ch) if ((tile) < NT) { \
    const bf16* s_ = gA + (tile) * 64 + (ch) * 32; \
    char* d_ = lds + ((tile) & 1) * 65536 + (ch) * 16384 + tid * 16; \
    GLDS16(s_, d_); GLDS16(s_ + (long)128 * K, d_ + 8192); }

#define STB(tile, ch) if ((tile) < NT) { \
    const bf16* s_ = gB + (tile) * 64 + (ch) * 32; \
    char* d_ = lds + ((tile) & 1) * 65536 + 32768 + (ch) * 16384 + tid * 16; \
    GLDS16(s_, d_); GLDS16(s_ + (long)128 * K, d_ + 8192); }

#define PH(tb, mh, kh, RB, STAGE_STMT, WAITN) do { \
    { const char* Ab_ = lds + (tb) * 65536 + (kh) * 16384; \
      const char* Bb_ = lds + (tb) * 65536 + 32768 + (kh) * 16384; \
      if (RB) { \
        _Pragma("unroll") for (int n_ = 0; n_ < 4; ++n_) \
          bfrag[n_] = *(const bf16x8*)(Bb_ + (wc * 64 + n_ * 16 + fr) * 64 + aslot); } \
      _Pragma("unroll") for (int i_ = 0; i_ < 4; ++i_) \
          afrag[i_] = *(const bf16x8*)(Ab_ + (wr * 128 + (mh) * 64 + i_ * 16 + fr) * 64 + aslot); \
    } \
    STAGE_STMT; \
    asm volatile("s_waitcnt vmcnt(" #WAITN ")" ::: "memory"); \
    asm volatile("s_barrier" ::: "memory"); \
    __builtin_amdgcn_s_setprio(1); \
    _Pragma("unroll") for (int n_ = 0; n_ < 4; ++n_) \
      _Pragma("unroll") for (int i_ = 0; i_ < 4; ++i_) \
        acc[(mh) * 4 + i_][n_] = __builtin_amdgcn_mfma_f32_16x16x32_bf16(afrag[i_], bfrag[n_], acc[(mh) * 4 + i_][n_], 0, 0, 0); \
    __builtin_amdgcn_s_setprio(0); \
    asm volatile("s_barrier" ::: "memory"); \
} while (0)

__global__ __launch_bounds__(512, 2) void gemm8p_sk(const bf16* __restrict__ A_,
                                                    const bf16* __restrict__ BT_,
                                                    bf16* __restrict__ part,
                                                    int M, int N, int K, int kch) {
    __shared__ __align__(16) char lds[131072];

    int bx = blockIdx.x, by = blockIdx.y;
    int k0base = blockIdx.z * kch;
    int bm = bx * 256, bn = by * 256;
    int NT = kch >> 6;

    int tid = threadIdx.x;
    int w = tid >> 6, l = tid & 63;
    int wr = w >> 2, wc = w & 3;
    int fr = l & 15;
    int aslot = (((l >> 4) ^ ((fr >> 1) & 3)) << 4);

    int srow0 = tid >> 2;
    int sgoff = (((tid & 3) ^ ((srow0 >> 1) & 3)) << 3);
    const bf16* gA = A_ + (long)(bm + srow0) * K + k0base + sgoff;
    const bf16* gB = BT_ + (long)(bn + srow0) * K + k0base + sgoff;

    f32x4 acc[8][4] = {};
    bf16x8 bfrag[4];
    bf16x8 afrag[4];

    STA(0, 0); STA(0, 1); STB(0, 0); STB(0, 1);
    STB(1, 0); STA(1, 0); STB(1, 1);
    asm volatile("s_waitcnt vmcnt(0)" ::: "memory");
    asm volatile("s_barrier" ::: "memory");

    int NI = NT >> 1;
    for (int i = 0; i < NI; ++i) {
        int t1 = 2 * i + 1, t2 = 2 * i + 2, t3 = 2 * i + 3;
        if (i == NI - 1) {
            PH(0, 0, 0, true, STA(t1, 1), 0);
        } else {
            PH(0, 0, 0, true, STA(t1, 1), 10);
        }
        PH(0, 1, 0, false, STB(t2, 0), 10);
        PH(0, 0, 1, true,  STA(t2, 0), 10);
        PH(0, 1, 1, false, STB(t2, 1), 10);
        PH(1, 0, 0, true,  STA(t2, 1), 10);
        PH(1, 1, 0, false, STB(t3, 0), 10);
        PH(1, 0, 1, true,  STA(t3, 0), 10);
        PH(1, 1, 1, false, STB(t3, 1), 10);
    }

    bf16* cz = part + (long)blockIdx.z * M * N;
    int r4 = (l >> 4) * 4;
#pragma unroll
    for (int mi = 0; mi < 8; ++mi) {
        int row = bm + wr * 128 + mi * 16 + r4;
#pragma unroll
        for (int n = 0; n < 4; ++n) {
            int col = bn + wc * 64 + n * 16 + fr;
#pragma unroll
            for (int r = 0; r < 4; ++r)
                cz[(long)(row + r) * N + col] = (bf16)acc[mi][n][r];
        }
    }
}

// out[i] = b2[i & 1023] + sum_z part[z][i]   (bf16 partials, N = 1024)
__global__ __launch_bounds__(256) void reduce4_kernel(const bf16* __restrict__ part,
                                                      const float* __restrict__ b2,
                                                      float* __restrict__ out) {
    const long stride = 4096L * 1024;
    long e0 = ((long)blockIdx.x * 256 + threadIdx.x) * 8;
    float s[8];
    int boff = (int)(e0 & 1023);
#pragma unroll
    for (int j = 0; j < 8; ++j) s[j] = b2[boff + j];
#pragma unroll
    for (int z = 0; z < 4; ++z) {
        bf16x8 v = *(const bf16x8*)&part[z * stride + e0];
#pragma unroll
        for (int j = 0; j < 8; ++j) s[j] += (float)v[j];
    }
    *(float4*)&out[e0] = *(float4*)&s[0];
    *(float4*)&out[e0 + 4] = *(float4*)&s[4];
}

// ---------------- V transpose: vsrc[4096][1024] -> vT[bh][d][lpos] ----------------
__global__ __launch_bounds__(256) void vtrans_kernel(const bf16* __restrict__ vsrc,
                                                     bf16* __restrict__ vT) {
    __shared__ unsigned short tile[64 * 65];
    int bh = blockIdx.x;
    int b = bh >> 4, hh = bh & 15;
    int l0 = blockIdx.y * 64;
    int tid = threadIdx.x;

    int r = tid >> 3, c = tid & 7;
#pragma unroll
    for (int p = 0; p < 2; ++p) {
        int row = r + p * 32;
        const bf16* src = vsrc + (long)(b * 2048 + l0 + row) * 1024 + hh * 64 + c * 8;
        bf16x8 v = *(const bf16x8*)src;
        union { bf16x8 v; unsigned short s[8]; } u; u.v = v;
#pragma unroll
        for (int e = 0; e < 8; ++e) tile[row * 65 + c * 8 + e] = u.s[e];
    }
    __syncthreads();
#pragma unroll
    for (int p = 0; p < 2; ++p) {
        int idx = tid + p * 256;
        int d = idx >> 3, kg = idx & 7;
        union { bf16x8 v; unsigned short s[8]; } u;
#pragma unroll
        for (int e = 0; e < 8; ++e) u.s[e] = tile[(kg * 8 + e) * 65 + d];
        *(bf16x8*)&vT[((long)bh * 64 + d) * 2048 + l0 + kg * 8] = u.v;
    }
}

// ---------------- Flash attention: in-register P via permlane32_swap ----------
__global__ __launch_bounds__(256) void attn_kernel(const bf16* __restrict__ qg,
                                                   const bf16* __restrict__ kg_,
                                                   const bf16* __restrict__ vT,
                                                   bf16* __restrict__ cat) {
    __shared__ __align__(16) char lds[49152];
    // K bufs: 0..24KB; V bufs: 24..48KB (3 rotating 8KB bufs each)

    int bidx = blockIdx.x;
    int bh = bidx & 31;
    int qblk = bidx >> 5;
    int b = bh >> 4, hh = bh & 15;
    int tid = threadIdx.x;
    int wv = tid >> 6, l = tid & 63;
    int h = l >> 5, ln = l & 31;
    int sw = (ln & 7) << 4;

    const bf16* qbase = qg + ((long)bh * 2048 + qblk * 128 + wv * 32 + ln) * 64 + h * 8;
    bf16x8 qf[4];
#pragma unroll
    for (int ds = 0; ds < 4; ++ds) qf[ds] = *(const bf16x8*)(qbase + ds * 16);

    f32x16 Oa0 = {}, Oa1 = {};
    float lsum = 0.0f;

    int kr = tid >> 3, kg = tid & 7;
    int swb = (kg * 16) ^ ((kr & 7) << 4);
    const bf16* gK = kg_ + ((long)bh * 2048 + kr) * 64 + kg * 8;
    const bf16* gV = vT + ((long)bh * 64 + kr) * 2048 + kg * 8;

    bf16x8 rk0 = *(const bf16x8*)gK;
    bf16x8 rk1 = *(const bf16x8*)(gK + 32 * 64);
    bf16x8 rv0 = *(const bf16x8*)gV;
    bf16x8 rv1 = *(const bf16x8*)(gV + 32 * 2048);
    *(bf16x8*)(lds + kr * 128 + swb) = rk0;
    *(bf16x8*)(lds + (kr + 32) * 128 + swb) = rk1;
    *(bf16x8*)(lds + 24576 + kr * 128 + swb) = rv0;
    *(bf16x8*)(lds + 24576 + (kr + 32) * 128 + swb) = rv1;
    __syncthreads();

    int bufR = 0;
    for (int t = 0; t < 32; ++t) {
        if (t < 31) {
            rk0 = *(const bf16x8*)(gK + (long)(t + 1) * 4096);
            rk1 = *(const bf16x8*)(gK + (long)(t + 1) * 4096 + 32 * 64);
            rv0 = *(const bf16x8*)(gV + (t + 1) * 64);
            rv1 = *(const bf16x8*)(gV + (t + 1) * 64 + 32 * 2048);
        }
        const char* Kc = lds + bufR * 8192;
        const char* Vc = lds + 24576 + bufR * 8192;

        f32x16 S0 = {}, S1 = {};
        __builtin_amdgcn_s_setprio(1);
#pragma unroll
        for (int ds = 0; ds < 4; ++ds) {
            bf16x8 kf0 = *(const bf16x8*)(Kc + ln * 128 + ((ds * 32 + h * 16) ^ sw));
            bf16x8 kf1 = *(const bf16x8*)(Kc + (32 + ln) * 128 + ((ds * 32 + h * 16) ^ sw));
            S0 = __builtin_amdgcn_mfma_f32_32x32x16_bf16(kf0, qf[ds], S0, 0, 0, 0);
            S1 = __builtin_amdgcn_mfma_f32_32x32x16_bf16(kf1, qf[ds], S1, 0, 0, 0);
        }
        __builtin_amdgcn_s_setprio(0);

        // ---- P = exp2(S - 12); assemble A-fragments fully in registers ----
        bf16x8 pa[4];
#pragma unroll
        for (int H = 0; H < 2; ++H) {
            float p[16];
#pragma unroll
            for (int r = 0; r < 16; ++r) {
                float v = ex2((H ? S1[r] : S0[r]) - 12.0f);
                p[r] = v;
                lsum += v;
            }
            unsigned w0[4], w1[4];
#pragma unroll
            for (int tt = 0; tt < 4; ++tt) {
                union { bf16 bb[2]; unsigned u; } pk0, pk1;
                pk0.bb[0] = (bf16)p[4 * tt + 0];
                pk0.bb[1] = (bf16)p[4 * tt + 1];
                pk1.bb[0] = (bf16)p[4 * tt + 2];
                pk1.bb[1] = (bf16)p[4 * tt + 3];
                w0[tt] = pk0.u;
                w1[tt] = pk1.u;
            }
#pragma unroll
            for (int sp = 0; sp < 2; ++sp) {
                unsigned A0 = w0[2 * sp], B0 = w0[2 * sp + 1];
                unsigned A1 = w1[2 * sp], B1 = w1[2 * sp + 1];
                plswap(h, A0, B0);
                plswap(h, A1, B1);
                union { unsigned u[4]; bf16x8 v; } pk;
                pk.u[0] = A0; pk.u[1] = A1; pk.u[2] = B0; pk.u[3] = B1;
                pa[H * 2 + sp] = pk.v;
            }
        }

        __builtin_amdgcn_s_setprio(1);
#pragma unroll
        for (int s = 0; s < 4; ++s) {
            bf16x8 vf0 = *(const bf16x8*)(Vc + ln * 128 + ((s * 32 + h * 16) ^ sw));
            bf16x8 vf1 = *(const bf16x8*)(Vc + (32 + ln) * 128 + ((s * 32 + h * 16) ^ sw));
            Oa0 = __builtin_amdgcn_mfma_f32_32x32x16_bf16(pa[s], vf0, Oa0, 0, 0, 0);
            Oa1 = __builtin_amdgcn_mfma_f32_32x32x16_bf16(pa[s], vf1, Oa1, 0, 0, 0);
        }
        __builtin_amdgcn_s_setprio(0);

        if (t < 31) {
            int bufW = (bufR == 2) ? 0 : bufR + 1;
            *(bf16x8*)(lds + bufW * 8192 + kr * 128 + swb) = rk0;
            *(bf16x8*)(lds + bufW * 8192 + (kr + 32) * 128 + swb) = rk1;
            *(bf16x8*)(lds + 24576 + bufW * 8192 + kr * 128 + swb) = rv0;
            *(bf16x8*)(lds + 24576 + bufW * 8192 + (kr + 32) * 128 + swb) = rv1;
        }
        __syncthreads();
        bufR = (bufR == 2) ? 0 : bufR + 1;
    }

    lsum += __shfl_xor(lsum, 32, 64);

#pragma unroll
    for (int r = 0; r < 16; ++r) {
        int rowq = (r & 3) + 8 * (r >> 2) + 4 * h;
        float ls = __shfl(lsum, rowq, 64);
        float inv = 1.0f / ls;
        long trow = (long)b * 2048 + qblk * 128 + wv * 32 + rowq;
        cat[trow * 5120 + hh * 64 + ln] = (bf16)(Oa0[r] * inv);
        cat[trow * 5120 + hh * 64 + 32 + ln] = (bf16)(Oa1[r] * inv);
    }
}

// ---------------- launch ----------------

extern "C" void kernel_launch(void* const* d_in, const int* in_sizes, int n_in,
                              void* d_out, int out_size, void* d_ws, size_t ws_size,
                              hipStream_t stream) {
    const float* x  = (const float*)d_in[0];
    const float* pe = (const float*)d_in[1];
    const float* W1 = (const float*)d_in[2];
    const float* b1 = (const float*)d_in[3];
    const float* W2 = (const float*)d_in[4];
    const float* b2 = (const float*)d_in[5];
    const float* qs = (const float*)d_in[6];
    const float* ks = (const float*)d_in[7];
    float* out = (float*)d_out;

    char* ws = (char*)d_ws;
    bf16* xb   = (bf16*)(ws);                 // 4096*1024*2      =  8388608
    bf16* w1t  = (bf16*)(ws + 8388608);       // 7168*1024*2     = 14680064
    bf16* w2t  = (bf16*)(ws + 23068672);      // 1024*5120*2     = 10485760
    bf16* vsrc = (bf16*)(ws + 33554432);      // 4096*1024*2     =  8388608
    bf16* qb   = (bf16*)(ws + 92274688);      // 32*2048*64*2    =  8388608
    bf16* kb   = (bf16*)(ws + 100663296);     //                 =  8388608
    bf16* vT   = (bf16*)(ws + 109051904);     //                 =  8388608
    bf16* cat  = (bf16*)(ws + 117440512);     // 4096*5120*2     = 41943040
    // bf16 split-K partials (4 x 4096 x 1024 x 2B) overlap vsrc/qb (dead by then).
    bf16* part = (bf16*)(ws + 33554432);

    prep_kernel<<<16384, 256, 0, stream>>>(x, xb, W1, w1t, W2, w2t);

    // GEMM1 + bias + fused {rmsnorm+rope -> qb/kb | vsrc | gelu -> cat}
    gemm1_fused<<<dim3(32, 56), 256, 0, stream>>>(xb, w1t, b1, pe, qs, ks,
                                                  qb, kb, vsrc, cat, 1024);

    vtrans_kernel<<<dim3(32, 32), 256, 0, stream>>>(vsrc, vT);

    attn_kernel<<<512, 256, 0, stream>>>(qb, kb, vT, cat);

    gemm8p_sk<<<dim3(16, 4, 4), 512, 0, stream>>>(cat, w2t, part, 4096, 1024, 5120, 1280);
    reduce4_kernel<<<2048, 256, 0, stream>>>(part, b2, out);
}